// Round 4
// baseline (77.268 us; speedup 1.0000x reference)
//
#include <hip/hip_runtime.h>
#include <hip/hip_bf16.h>

#define N_NODES 4096
#define C_IN    1024
#define H_HEADS 4
#define D_HEAD  128
#define C_OUT   512   // H_HEADS * D_HEAD
#define DEG_CAP 256   // max compacted degree; Binom(4096,0.02) mean 82, 17-sigma safe

typedef __attribute__((ext_vector_type(8))) short short8;
typedef __attribute__((ext_vector_type(8))) unsigned short u16x8;
typedef __attribute__((ext_vector_type(4))) float f32x4;

__device__ __forceinline__ unsigned short f2bf(float f) {
    unsigned u = __float_as_uint(f);
    u += 0x7FFFu + ((u >> 16) & 1u);   // RNE
    return (unsigned short)(u >> 16);
}
__device__ __forceinline__ float bf2f(unsigned short u) {
    return __uint_as_float((unsigned)u << 16);
}
__device__ __forceinline__ float sigv(float s) {
    return 1.f / (1.f + __expf(-s)) - 0.5f;
}

#define GLOAD_LDS16(gp, lp)                                                        \
    __builtin_amdgcn_global_load_lds(                                              \
        (const __attribute__((address_space(1))) unsigned int*)(gp),               \
        (__attribute__((address_space(3))) unsigned int*)(lp), 16, 0, 0)

// ---------- kernel 0: X [N][C_IN] f32 -> bf16
__global__ void k_xb(const float* __restrict__ X, unsigned short* __restrict__ Xb) {
    int g = blockIdx.x * blockDim.x + threadIdx.x;   // each thread: 8 elems
    const float4* s = (const float4*)(X + (size_t)g * 8);
    float4 a = s[0], b = s[1];
    ushort4 p0, p1;
    p0.x = f2bf(a.x); p0.y = f2bf(a.y); p0.z = f2bf(a.z); p0.w = f2bf(a.w);
    p1.x = f2bf(b.x); p1.y = f2bf(b.y); p1.z = f2bf(b.z); p1.w = f2bf(b.w);
    ushort4* d = (ushort4*)(Xb + (size_t)g * 8);
    d[0] = p0; d[1] = p1;
}

// ---------- kernel 1: W [H][C][D] f32 -> Wt [(h*D+d)][C] bf16 (B^T layout)
__global__ void k_wt(const float* __restrict__ W, unsigned short* __restrict__ Wt) {
    int g = blockIdx.x * blockDim.x + threadIdx.x;
    int o = g * 4;                                   // o = (h*128+d)*1024 + c
    int c  = o & 1023;
    int hd = o >> 10;
    int d  = hd & 127;
    int h  = hd >> 7;
    const float* src = W + (size_t)h * C_IN * D_HEAD + (size_t)c * D_HEAD + d;
    ushort4 p;
    p.x = f2bf(src[0 * D_HEAD]);
    p.y = f2bf(src[1 * D_HEAD]);
    p.z = f2bf(src[2 * D_HEAD]);
    p.w = f2bf(src[3 * D_HEAD]);
    *(ushort4*)(Wt + o) = p;
}

// ---------- kernel 2: Hb[N][512] (bf16) = Xb @ Wt^T + b
// BM=64, BN=64, BK=64; grid 512 (2 blocks/CU); 4 waves, 32x32 each.
__global__ void k_gemm(const unsigned short* __restrict__ Xb,
                       const unsigned short* __restrict__ Wt,
                       const float* __restrict__ bias, unsigned short* __restrict__ Hb) {
    __shared__ __align__(16) unsigned short ldsA[2 * 64 * 32];   // 8 KB
    __shared__ __align__(16) unsigned short ldsB[2 * 64 * 32];   // 8 KB
    const int t    = threadIdx.x;
    const int lane = t & 63;
    const int wid  = t >> 6;
    const int wrow = wid >> 1, wcol = wid & 1;
    const int bid  = blockIdx.x;
    const int lin  = (bid & 7) * 64 + (bid >> 3);   // bijective XCD swizzle (512 = 8*64)
    const int rowStart = (lin >> 3) * 64;
    const int colStart = (lin & 7) * 64;

    f32x4 acc[2][2];
#pragma unroll
    for (int m = 0; m < 2; ++m)
#pragma unroll
        for (int n = 0; n < 2; ++n) acc[m][n] = (f32x4){0.f, 0.f, 0.f, 0.f};

    const int lrow = lane >> 2;   // 0..15
    const int lkq  = lane & 3;    // 0..3

    for (int k0 = 0; k0 < C_IN; k0 += 64) {
        // A: 8 chunks of 1 KB (16 rows x 32 k-half), 2 per wave
#pragma unroll
        for (int i = 0; i < 2; ++i) {
            int c  = wid * 2 + i;          // wave-uniform
            int h  = c >> 2, rb = c & 3;
            const unsigned short* g =
                Xb + (size_t)(rowStart + rb * 16 + lrow) * C_IN + k0 + h * 32 + lkq * 8;
            GLOAD_LDS16(g, ldsA + h * 2048 + rb * 512);
        }
        // B: 8 chunks, 2 per wave
#pragma unroll
        for (int i = 0; i < 2; ++i) {
            int c  = wid * 2 + i;
            int h  = c >> 2, db = c & 3;
            const unsigned short* g =
                Wt + (size_t)(colStart + db * 16 + lrow) * C_IN + k0 + h * 32 + lkq * 8;
            GLOAD_LDS16(g, ldsB + h * 2048 + db * 512);
        }
        __syncthreads();

        const int fo = (lane >> 4) * 8;
        const int fr = lane & 15;
#pragma unroll
        for (int h = 0; h < 2; ++h) {
            short8 bfr[2];
#pragma unroll
            for (int n = 0; n < 2; ++n)
                bfr[n] = *(const short8*)(ldsB + h * 2048 + (wcol * 32 + n * 16 + fr) * 32 + fo);
#pragma unroll
            for (int m = 0; m < 2; ++m) {
                short8 a = *(const short8*)(ldsA + h * 2048 + (wrow * 32 + m * 16 + fr) * 32 + fo);
#pragma unroll
                for (int n = 0; n < 2; ++n)
                    acc[m][n] = __builtin_amdgcn_mfma_f32_16x16x32_bf16(a, bfr[n], acc[m][n], 0, 0, 0);
            }
        }
        __syncthreads();
    }

    // epilogue: bf16 store; C layout col=lane&15, row=(lane>>4)*4+r
#pragma unroll
    for (int m = 0; m < 2; ++m) {
        int row_g = rowStart + wrow * 32 + m * 16 + (lane >> 4) * 4;
#pragma unroll
        for (int n = 0; n < 2; ++n) {
            int col_g = colStart + wcol * 32 + n * 16 + (lane & 15);
            float bb = bias[col_g];
#pragma unroll
            for (int r = 0; r < 4; ++r)
                Hb[(size_t)(row_g + r) * C_OUT + col_g] = f2bf(acc[m][n][r] + bb);
        }
    }
}

// ---------- kernel 3: per-row: F1/F2 from Hb + adj compaction -> idx/nnz (CSR)
__global__ void k_prep(const float* __restrict__ adj, const unsigned short* __restrict__ Hb,
                       const float* __restrict__ v0, const float* __restrict__ v1,
                       float* __restrict__ F1, float* __restrict__ F2,
                       unsigned short* __restrict__ idx, int* __restrict__ nnz) {
    __shared__ int wtot[4];
    const int i    = blockIdx.x;
    const int t    = threadIdx.x;
    const int lane = t & 63;
    const int wid  = t >> 6;

    // issue adj loads early
    const float4* arow = (const float4*)(adj + (size_t)i * N_NODES);
    float4 av[4];
#pragma unroll
    for (int r = 0; r < 4; ++r) av[r] = arow[r * 256 + t];

    // ---- F1/F2 from bf16 Hb (warp w == head w: cols 128w..128w+127)
    int c = 2 * t;
    unsigned int hp = *(const unsigned int*)(Hb + (size_t)i * C_OUT + c);
    float h0 = bf2f((unsigned short)(hp & 0xFFFFu));
    float h1 = bf2f((unsigned short)(hp >> 16));
    float s1 = h0 * v0[c] + h1 * v0[c + 1];
    float s2 = h0 * v1[c] + h1 * v1[c + 1];
#pragma unroll
    for (int off = 32; off; off >>= 1) {
        s1 += __shfl_xor(s1, off);
        s2 += __shfl_xor(s2, off);
    }
    if (lane == 0) {
        F1[i * 4 + wid] = s1;
        F2[i * 4 + wid] = s2;
    }

    // ---- compaction
    int cnt = 0;
#pragma unroll
    for (int r = 0; r < 4; ++r)
        cnt += (av[r].x != 0.f) + (av[r].y != 0.f) + (av[r].z != 0.f) + (av[r].w != 0.f);
    int v = cnt;
#pragma unroll
    for (int off = 1; off < 64; off <<= 1) {
        int u = __shfl_up(v, off);
        if (lane >= off) v += u;
    }
    if (lane == 63) wtot[wid] = v;
    __syncthreads();
    int wpre = 0, total = 0;
#pragma unroll
    for (int w = 0; w < 4; ++w) {
        int tw = wtot[w];
        if (w < wid) wpre += tw;
        total += tw;
    }
    int off = wpre + v - cnt;
    unsigned short* ir = idx + (size_t)i * DEG_CAP;
#pragma unroll
    for (int r = 0; r < 4; ++r) {
        int j0 = (r * 256 + t) * 4;
        if (av[r].x != 0.f) { if (off < DEG_CAP) ir[off] = (unsigned short)j0;       off++; }
        if (av[r].y != 0.f) { if (off < DEG_CAP) ir[off] = (unsigned short)(j0 + 1); off++; }
        if (av[r].z != 0.f) { if (off < DEG_CAP) ir[off] = (unsigned short)(j0 + 2); off++; }
        if (av[r].w != 0.f) { if (off < DEG_CAP) ir[off] = (unsigned short)(j0 + 3); off++; }
    }
    if (t == 0) nnz[i] = min(total, DEG_CAP);
}

// ---------- kernel 4: per-row softmax + PV gather
__global__ void k_pv(const unsigned short* __restrict__ idx, const int* __restrict__ nnz,
                     const float* __restrict__ F1, const float* __restrict__ F2,
                     const unsigned short* __restrict__ Hb, float* __restrict__ Out) {
    __shared__ float partial[4][C_OUT];   // 8 KB
    __shared__ float redm[16];
    __shared__ float redd[16];
    const int i    = blockIdx.x;
    const int t    = threadIdx.x;
    const int lane = t & 63;
    const int wid  = t >> 6;
    const int headl = lane >> 4;

    const int nv = nnz[i];
    float4 f1v = *(const float4*)(F1 + i * 4);
    const unsigned short* __restrict__ ji = idx + (size_t)i * DEG_CAP;

    // ---- per-head row max
    float mx[4] = {-1e30f, -1e30f, -1e30f, -1e30f};
    for (int jj = t; jj < nv; jj += 256) {
        int j = ji[jj];
        float4 f2v = *(const float4*)(F2 + j * 4);
        float s0 = f1v.x + f2v.x, s1 = f1v.y + f2v.y;
        float s2 = f1v.z + f2v.z, s3 = f1v.w + f2v.w;
        if (s0 != 0.f) mx[0] = fmaxf(mx[0], sigv(s0));
        if (s1 != 0.f) mx[1] = fmaxf(mx[1], sigv(s1));
        if (s2 != 0.f) mx[2] = fmaxf(mx[2], sigv(s2));
        if (s3 != 0.f) mx[3] = fmaxf(mx[3], sigv(s3));
    }
#pragma unroll
    for (int h = 0; h < 4; ++h)
#pragma unroll
        for (int o2 = 32; o2; o2 >>= 1) mx[h] = fmaxf(mx[h], __shfl_xor(mx[h], o2));
    if (lane == 0) {
        redm[wid * 4 + 0] = mx[0]; redm[wid * 4 + 1] = mx[1];
        redm[wid * 4 + 2] = mx[2]; redm[wid * 4 + 3] = mx[3];
    }
    __syncthreads();

    // per-lane head-resolved constants (no dynamic register indexing)
    float f1h = (headl == 0) ? f1v.x : (headl == 1) ? f1v.y : (headl == 2) ? f1v.z : f1v.w;
    float rmh = fmaxf(fmaxf(redm[0 + headl], redm[4 + headl]),
                      fmaxf(redm[8 + headl], redm[12 + headl]));

    // ---- warp-parallel exp + PV (warp w handles entries w, w+4, ...)
    float acc[8];
#pragma unroll
    for (int k = 0; k < 8; ++k) acc[k] = 0.f;
    float dsum = 0.f;
    const unsigned short* __restrict__ hp = Hb + lane * 8;
#pragma unroll 4
    for (int jj = wid; jj < nv; jj += 4) {
        int j = ji[jj];
        float s = f1h + F2[j * 4 + headl];
        float e = (s != 0.f) ? __expf(sigv(s) - rmh) : 0.f;
        dsum += e;
        u16x8 hv = *(const u16x8*)(hp + (size_t)j * C_OUT);
#pragma unroll
        for (int k = 0; k < 8; ++k) acc[k] += e * bf2f(hv[k]);
    }

    f32x4 lo = {acc[0], acc[1], acc[2], acc[3]};
    f32x4 hi = {acc[4], acc[5], acc[6], acc[7]};
    *(f32x4*)&partial[wid][lane * 8]     = lo;
    *(f32x4*)&partial[wid][lane * 8 + 4] = hi;
    if ((lane & 15) == 0) redd[wid * 4 + headl] = dsum;
    __syncthreads();

    int head = t >> 6;
    float dn = redd[0 + head] + redd[4 + head] + redd[8 + head] + redd[12 + head];
    int c = 2 * t;
    float s0 = partial[0][c] + partial[1][c] + partial[2][c] + partial[3][c];
    float s1 = partial[0][c + 1] + partial[1][c + 1] + partial[2][c + 1] + partial[3][c + 1];
    float2 o;
    if (dn > 0.f) {
        float inv = 1.f / fmaxf(dn, 1e-30f);
        o.x = s0 * inv;
        o.y = s1 * inv;
    } else {
        o.x = 0.f; o.y = 0.f;
    }
    *(float2*)(Out + (size_t)i * C_OUT + c) = o;
}

// ---------- launch
extern "C" void kernel_launch(void* const* d_in, const int* in_sizes, int n_in,
                              void* d_out, int out_size, void* d_ws, size_t ws_size,
                              hipStream_t stream) {
    const float* X   = (const float*)d_in[0];
    const float* adj = (const float*)d_in[1];
    const float* W   = (const float*)d_in[2];
    const float* b   = (const float*)d_in[3];
    const float* v0  = (const float*)d_in[4];
    const float* v1  = (const float*)d_in[5];
    float* out = (float*)d_out;

    char* ws = (char*)d_ws;
    unsigned short* Wt  = (unsigned short*)ws;                                   // 1 MB
    unsigned short* Xb  = (unsigned short*)(ws + (size_t)1 * 1024 * 1024);       // 8 MB
    unsigned short* Hb  = (unsigned short*)(ws + (size_t)9 * 1024 * 1024);       // 4 MB
    float*          F1  = (float*)(ws + (size_t)13 * 1024 * 1024);               // 64 KB
    float*          F2  = F1 + N_NODES * 4;                                      // 64 KB
    unsigned short* idx = (unsigned short*)(ws + (size_t)14 * 1024 * 1024);      // 2 MB
    int*            nnz = (int*)(ws + (size_t)16 * 1024 * 1024);                 // 16 KB

    k_xb<<<2048, 256, 0, stream>>>(X, Xb);
    k_wt<<<512, 256, 0, stream>>>(W, Wt);
    k_gemm<<<512, 256, 0, stream>>>(Xb, Wt, b, Hb);
    k_prep<<<N_NODES, 256, 0, stream>>>(adj, Hb, v0, v1, F1, F2, idx, nnz);
    k_pv<<<N_NODES, 256, 0, stream>>>(idx, nnz, F1, F2, Hb, out);
}

// Round 5
// 60.827 us; speedup vs baseline: 1.2703x; 1.2703x over previous
//
#include <hip/hip_runtime.h>
#include <hip/hip_bf16.h>

#define N_NODES 4096
#define C_IN    1024
#define H_HEADS 4
#define D_HEAD  128
#define C_OUT   512   // H_HEADS * D_HEAD
#define DEG_CAP 256   // max compacted degree; Binom(4096,0.02) mean 82, 17-sigma safe

typedef __attribute__((ext_vector_type(8))) short short8;
typedef __attribute__((ext_vector_type(8))) unsigned short u16x8;
typedef __attribute__((ext_vector_type(4))) float f32x4;

__device__ __forceinline__ unsigned short f2bf(float f) {
    unsigned u = __float_as_uint(f);
    u += 0x7FFFu + ((u >> 16) & 1u);   // RNE
    return (unsigned short)(u >> 16);
}
__device__ __forceinline__ float bf2f(unsigned short u) {
    return __uint_as_float((unsigned)u << 16);
}
__device__ __forceinline__ float sigv(float s) {
    return 1.f / (1.f + __expf(-s)) - 0.5f;
}

#define GLOAD_LDS16(gp, lp)                                                        \
    __builtin_amdgcn_global_load_lds(                                              \
        (const __attribute__((address_space(1))) unsigned int*)(gp),               \
        (__attribute__((address_space(3))) unsigned int*)(lp), 16, 0, 0)

// ---------- kernel 0: X [N][C_IN] f32 -> bf16
__global__ void k_xb(const float* __restrict__ X, unsigned short* __restrict__ Xb) {
    int g = blockIdx.x * blockDim.x + threadIdx.x;   // each thread: 8 elems
    const float4* s = (const float4*)(X + (size_t)g * 8);
    float4 a = s[0], b = s[1];
    ushort4 p0, p1;
    p0.x = f2bf(a.x); p0.y = f2bf(a.y); p0.z = f2bf(a.z); p0.w = f2bf(a.w);
    p1.x = f2bf(b.x); p1.y = f2bf(b.y); p1.z = f2bf(b.z); p1.w = f2bf(b.w);
    ushort4* d = (ushort4*)(Xb + (size_t)g * 8);
    d[0] = p0; d[1] = p1;
}

// ---------- kernel 1: W [H][C][D] f32 -> Wt [(h*D+d)][C] bf16 (B^T layout)
__global__ void k_wt(const float* __restrict__ W, unsigned short* __restrict__ Wt) {
    int g = blockIdx.x * blockDim.x + threadIdx.x;
    int o = g * 4;                                   // o = (h*128+d)*1024 + c
    int c  = o & 1023;
    int hd = o >> 10;
    int d  = hd & 127;
    int h  = hd >> 7;
    const float* src = W + (size_t)h * C_IN * D_HEAD + (size_t)c * D_HEAD + d;
    ushort4 p;
    p.x = f2bf(src[0 * D_HEAD]);
    p.y = f2bf(src[1 * D_HEAD]);
    p.z = f2bf(src[2 * D_HEAD]);
    p.w = f2bf(src[3 * D_HEAD]);
    *(ushort4*)(Wt + o) = p;
}

// ---------- kernel 2: Hb[N][512] (bf16) = Xb @ Wt^T + b
// BM=64, BN=64, BK=64; grid 512 (2 blocks/CU); 4 waves, 32x32 each.
__global__ void k_gemm(const unsigned short* __restrict__ Xb,
                       const unsigned short* __restrict__ Wt,
                       const float* __restrict__ bias, unsigned short* __restrict__ Hb) {
    __shared__ __align__(16) unsigned short ldsA[2 * 64 * 32];   // 8 KB
    __shared__ __align__(16) unsigned short ldsB[2 * 64 * 32];   // 8 KB
    const int t    = threadIdx.x;
    const int lane = t & 63;
    const int wid  = t >> 6;
    const int wrow = wid >> 1, wcol = wid & 1;
    const int bid  = blockIdx.x;
    const int lin  = (bid & 7) * 64 + (bid >> 3);   // bijective XCD swizzle (512 = 8*64)
    const int rowStart = (lin >> 3) * 64;
    const int colStart = (lin & 7) * 64;

    f32x4 acc[2][2];
#pragma unroll
    for (int m = 0; m < 2; ++m)
#pragma unroll
        for (int n = 0; n < 2; ++n) acc[m][n] = (f32x4){0.f, 0.f, 0.f, 0.f};

    const int lrow = lane >> 2;   // 0..15
    const int lkq  = lane & 3;    // 0..3

    for (int k0 = 0; k0 < C_IN; k0 += 64) {
        // A: 8 chunks of 1 KB (16 rows x 32 k-half), 2 per wave
#pragma unroll
        for (int i = 0; i < 2; ++i) {
            int c  = wid * 2 + i;          // wave-uniform
            int h  = c >> 2, rb = c & 3;
            const unsigned short* g =
                Xb + (size_t)(rowStart + rb * 16 + lrow) * C_IN + k0 + h * 32 + lkq * 8;
            GLOAD_LDS16(g, ldsA + h * 2048 + rb * 512);
        }
        // B: 8 chunks, 2 per wave
#pragma unroll
        for (int i = 0; i < 2; ++i) {
            int c  = wid * 2 + i;
            int h  = c >> 2, db = c & 3;
            const unsigned short* g =
                Wt + (size_t)(colStart + db * 16 + lrow) * C_IN + k0 + h * 32 + lkq * 8;
            GLOAD_LDS16(g, ldsB + h * 2048 + db * 512);
        }
        __syncthreads();

        const int fo = (lane >> 4) * 8;
        const int fr = lane & 15;
#pragma unroll
        for (int h = 0; h < 2; ++h) {
            short8 bfr[2];
#pragma unroll
            for (int n = 0; n < 2; ++n)
                bfr[n] = *(const short8*)(ldsB + h * 2048 + (wcol * 32 + n * 16 + fr) * 32 + fo);
#pragma unroll
            for (int m = 0; m < 2; ++m) {
                short8 a = *(const short8*)(ldsA + h * 2048 + (wrow * 32 + m * 16 + fr) * 32 + fo);
#pragma unroll
                for (int n = 0; n < 2; ++n)
                    acc[m][n] = __builtin_amdgcn_mfma_f32_16x16x32_bf16(a, bfr[n], acc[m][n], 0, 0, 0);
            }
        }
        __syncthreads();
    }

    // epilogue: bf16 store; C layout col=lane&15, row=(lane>>4)*4+r
#pragma unroll
    for (int m = 0; m < 2; ++m) {
        int row_g = rowStart + wrow * 32 + m * 16 + (lane >> 4) * 4;
#pragma unroll
        for (int n = 0; n < 2; ++n) {
            int col_g = colStart + wcol * 32 + n * 16 + (lane & 15);
            float bb = bias[col_g];
#pragma unroll
            for (int r = 0; r < 4; ++r)
                Hb[(size_t)(row_g + r) * C_OUT + col_g] = f2bf(acc[m][n][r] + bb);
        }
    }
}

// ---------- kernel 3: per-row: F1/F2 from Hb + adj compaction -> idx/nnz (CSR)
__global__ void k_prep(const float* __restrict__ adj, const unsigned short* __restrict__ Hb,
                       const float* __restrict__ v0, const float* __restrict__ v1,
                       float* __restrict__ F1, float* __restrict__ F2,
                       unsigned short* __restrict__ idx, int* __restrict__ nnz) {
    __shared__ int wtot[4];
    const int i    = blockIdx.x;
    const int t    = threadIdx.x;
    const int lane = t & 63;
    const int wid  = t >> 6;

    // issue adj loads early
    const float4* arow = (const float4*)(adj + (size_t)i * N_NODES);
    float4 av[4];
#pragma unroll
    for (int r = 0; r < 4; ++r) av[r] = arow[r * 256 + t];

    // ---- F1/F2 from bf16 Hb (warp w == head w: cols 128w..128w+127)
    int c = 2 * t;
    unsigned int hp = *(const unsigned int*)(Hb + (size_t)i * C_OUT + c);
    float h0 = bf2f((unsigned short)(hp & 0xFFFFu));
    float h1 = bf2f((unsigned short)(hp >> 16));
    float s1 = h0 * v0[c] + h1 * v0[c + 1];
    float s2 = h0 * v1[c] + h1 * v1[c + 1];
#pragma unroll
    for (int off = 32; off; off >>= 1) {
        s1 += __shfl_xor(s1, off);
        s2 += __shfl_xor(s2, off);
    }
    if (lane == 0) {
        F1[i * 4 + wid] = s1;
        F2[i * 4 + wid] = s2;
    }

    // ---- compaction
    int cnt = 0;
#pragma unroll
    for (int r = 0; r < 4; ++r)
        cnt += (av[r].x != 0.f) + (av[r].y != 0.f) + (av[r].z != 0.f) + (av[r].w != 0.f);
    int v = cnt;
#pragma unroll
    for (int off = 1; off < 64; off <<= 1) {
        int u = __shfl_up(v, off);
        if (lane >= off) v += u;
    }
    if (lane == 63) wtot[wid] = v;
    __syncthreads();
    int wpre = 0, total = 0;
#pragma unroll
    for (int w = 0; w < 4; ++w) {
        int tw = wtot[w];
        if (w < wid) wpre += tw;
        total += tw;
    }
    int off = wpre + v - cnt;
    unsigned short* ir = idx + (size_t)i * DEG_CAP;
#pragma unroll
    for (int r = 0; r < 4; ++r) {
        int j0 = (r * 256 + t) * 4;
        if (av[r].x != 0.f) { if (off < DEG_CAP) ir[off] = (unsigned short)j0;       off++; }
        if (av[r].y != 0.f) { if (off < DEG_CAP) ir[off] = (unsigned short)(j0 + 1); off++; }
        if (av[r].z != 0.f) { if (off < DEG_CAP) ir[off] = (unsigned short)(j0 + 2); off++; }
        if (av[r].w != 0.f) { if (off < DEG_CAP) ir[off] = (unsigned short)(j0 + 3); off++; }
    }
    if (t == 0) nnz[i] = min(total, DEG_CAP);
}

// ---------- kernel 4: per-row softmax (no-max: vals bounded in (-.5,.5)) + PV gather
__global__ void k_pv(const unsigned short* __restrict__ idx, const int* __restrict__ nnz,
                     const float* __restrict__ F1, const float* __restrict__ F2,
                     const unsigned short* __restrict__ Hb, float* __restrict__ Out) {
    __shared__ unsigned short jl[DEG_CAP];     // 512 B compacted indices
    __shared__ float ev[DEG_CAP * 4];          // 4 KB evals [entry][head]
    __shared__ float partial[4][C_OUT];        // 8 KB
    __shared__ float dred[4][4];               // [wave][head]
    const int i    = blockIdx.x;
    const int t    = threadIdx.x;
    const int lane = t & 63;
    const int wid  = t >> 6;
    const int headl = lane >> 4;

    const int nv = nnz[i];
    float4 f1v = *(const float4*)(F1 + i * 4);
    const unsigned short* __restrict__ ji = idx + (size_t)i * DEG_CAP;

    // ---- phase A: evals (one entry per thread; softmax is shift-invariant,
    // vals = sigmoid-0.5 in (-.5,.5) so exp(vals) in (0.6,1.65): no max pass needed)
    float d0 = 0.f, d1 = 0.f, d2 = 0.f, d3 = 0.f;
    for (int jj = t; jj < nv; jj += 256) {
        int j = ji[jj];
        jl[jj] = (unsigned short)j;
        float4 f2v = *(const float4*)(F2 + j * 4);
        float s0 = f1v.x + f2v.x, s1 = f1v.y + f2v.y;
        float s2 = f1v.z + f2v.z, s3 = f1v.w + f2v.w;
        float e0 = (s0 != 0.f) ? __expf(sigv(s0)) : 0.f;
        float e1 = (s1 != 0.f) ? __expf(sigv(s1)) : 0.f;
        float e2 = (s2 != 0.f) ? __expf(sigv(s2)) : 0.f;
        float e3 = (s3 != 0.f) ? __expf(sigv(s3)) : 0.f;
        ev[jj * 4 + 0] = e0; ev[jj * 4 + 1] = e1;
        ev[jj * 4 + 2] = e2; ev[jj * 4 + 3] = e3;
        d0 += e0; d1 += e1; d2 += e2; d3 += e3;
    }
#pragma unroll
    for (int o2 = 32; o2; o2 >>= 1) {
        d0 += __shfl_xor(d0, o2); d1 += __shfl_xor(d1, o2);
        d2 += __shfl_xor(d2, o2); d3 += __shfl_xor(d3, o2);
    }
    if (lane == 0) {
        dred[wid][0] = d0; dred[wid][1] = d1; dred[wid][2] = d2; dred[wid][3] = d3;
    }
    __syncthreads();

    // ---- phase B: PV gather, warp w -> entries w, w+4, ...; 2-way interleaved,
    // two acc banks; all loop operands from LDS so 8 row-gathers stay in flight.
    float acc0[8], acc1[8];
#pragma unroll
    for (int k = 0; k < 8; ++k) { acc0[k] = 0.f; acc1[k] = 0.f; }
    const unsigned short* __restrict__ hp = Hb + lane * 8;

    int jj = wid;
#pragma unroll 4
    for (; jj + 4 < nv; jj += 8) {
        int ja = jl[jj], jb = jl[jj + 4];
        float ea = ev[jj * 4 + headl];
        float eb = ev[(jj + 4) * 4 + headl];
        u16x8 ha = *(const u16x8*)(hp + (size_t)ja * C_OUT);
        u16x8 hb = *(const u16x8*)(hp + (size_t)jb * C_OUT);
#pragma unroll
        for (int k = 0; k < 8; ++k) acc0[k] += ea * bf2f(ha[k]);
#pragma unroll
        for (int k = 0; k < 8; ++k) acc1[k] += eb * bf2f(hb[k]);
    }
    if (jj < nv) {
        int ja = jl[jj];
        float ea = ev[jj * 4 + headl];
        u16x8 ha = *(const u16x8*)(hp + (size_t)ja * C_OUT);
#pragma unroll
        for (int k = 0; k < 8; ++k) acc0[k] += ea * bf2f(ha[k]);
    }

    f32x4 lo = {acc0[0] + acc1[0], acc0[1] + acc1[1], acc0[2] + acc1[2], acc0[3] + acc1[3]};
    f32x4 hi = {acc0[4] + acc1[4], acc0[5] + acc1[5], acc0[6] + acc1[6], acc0[7] + acc1[7]};
    *(f32x4*)&partial[wid][lane * 8]     = lo;
    *(f32x4*)&partial[wid][lane * 8 + 4] = hi;
    __syncthreads();

    int head = t >> 6;
    float dn = dred[0][head] + dred[1][head] + dred[2][head] + dred[3][head];
    int c = 2 * t;
    float s0 = partial[0][c] + partial[1][c] + partial[2][c] + partial[3][c];
    float s1 = partial[0][c + 1] + partial[1][c + 1] + partial[2][c + 1] + partial[3][c + 1];
    float2 o;
    if (dn > 0.f) {
        float inv = 1.f / fmaxf(dn, 1e-30f);
        o.x = s0 * inv;
        o.y = s1 * inv;
    } else {
        o.x = 0.f; o.y = 0.f;
    }
    *(float2*)(Out + (size_t)i * C_OUT + c) = o;
}

// ---------- launch
extern "C" void kernel_launch(void* const* d_in, const int* in_sizes, int n_in,
                              void* d_out, int out_size, void* d_ws, size_t ws_size,
                              hipStream_t stream) {
    const float* X   = (const float*)d_in[0];
    const float* adj = (const float*)d_in[1];
    const float* W   = (const float*)d_in[2];
    const float* b   = (const float*)d_in[3];
    const float* v0  = (const float*)d_in[4];
    const float* v1  = (const float*)d_in[5];
    float* out = (float*)d_out;

    char* ws = (char*)d_ws;
    unsigned short* Wt  = (unsigned short*)ws;                                   // 1 MB
    unsigned short* Xb  = (unsigned short*)(ws + (size_t)1 * 1024 * 1024);       // 8 MB
    unsigned short* Hb  = (unsigned short*)(ws + (size_t)9 * 1024 * 1024);       // 4 MB
    float*          F1  = (float*)(ws + (size_t)13 * 1024 * 1024);               // 64 KB
    float*          F2  = F1 + N_NODES * 4;                                      // 64 KB
    unsigned short* idx = (unsigned short*)(ws + (size_t)14 * 1024 * 1024);      // 2 MB
    int*            nnz = (int*)(ws + (size_t)16 * 1024 * 1024);                 // 16 KB

    k_xb<<<2048, 256, 0, stream>>>(X, Xb);
    k_wt<<<512, 256, 0, stream>>>(W, Wt);
    k_gemm<<<512, 256, 0, stream>>>(Xb, Wt, b, Hb);
    k_prep<<<N_NODES, 256, 0, stream>>>(adj, Hb, v0, v1, F1, F2, idx, nnz);
    k_pv<<<N_NODES, 256, 0, stream>>>(idx, nnz, F1, F2, Hb, out);
}